// Round 8
// baseline (1191.928 us; speedup 1.0000x reference)
//
#include <hip/hip_runtime.h>

typedef unsigned short u16;
typedef __bf16 bf16x8 __attribute__((ext_vector_type(8)));
typedef float f32x4 __attribute__((ext_vector_type(4)));

#define TOKENS 200704
#define QK_ELEMS 51380224UL   // 32768 pairs * 49 * 32 (each of Q,K,V)

__device__ __forceinline__ u16 f2b(float f) {
    __bf16 h = (__bf16)f;                 // hw v_cvt (RTNE)
    return __builtin_bit_cast(u16, h);
}

#define GLDS(g, l) __builtin_amdgcn_global_load_lds( \
    (const __attribute__((address_space(1))) void*)(g), \
    (__attribute__((address_space(3))) void*)(l), 16, 0, 0)

#define MFMA __builtin_amdgcn_mfma_f32_16x16x32_bf16

// ---------------------------------------------------------------------------
// GEMM: C[m,n] = sum_k A[m,k]*W[n,k].  256x256 tile, BK=64, 512 thr (8 waves
// 2Mx4N). Double-buffered 128 KB LDS, counted-vmcnt pipeline (T3/T4), setprio
// around MFMA clusters (T5), XOR-swizzled LDS (0 conflicts measured).
// EPI 0: qkv (+bias, q pre-scaled) -> (pair*49+pos)*32+d for Q,K,V (moff = row offset)
// EPI 1: proj: x2 = v+bias+res -> outf (f32)  AND fused LN2 -> h2o (bf16)
// EPI 2: fc1 (+bias, GELU -> bf16)   EPI 3: fc2 (+bias, outf +=)
// ---------------------------------------------------------------------------
template<int EPI>
__global__ __launch_bounds__(512, 2)
void gemm256(const u16* __restrict__ A, const u16* __restrict__ W,
             const float* __restrict__ bias, int nt, int K, long moff,
             u16* __restrict__ outb, float* __restrict__ outf,
             const float* __restrict__ res,
             const float* __restrict__ g2, const float* __restrict__ b2,
             u16* __restrict__ h2o)
{
    __shared__ u16 As[2][256 * 64];
    __shared__ u16 Bs[2][256 * 64];
    const int tid  = threadIdx.x;
    const int wave = tid >> 6, lane = tid & 63;

    // bijective XCD-aware block swizzle (m204)
    const int nwg = gridDim.x, bidO = blockIdx.x;
    const int qq = nwg >> 3, rr = nwg & 7;
    const int xcd = bidO & 7, idxx = bidO >> 3;
    const int bid = (xcd < rr) ? (xcd * (qq + 1) + idxx)
                               : (rr * (qq + 1) + (xcd - rr) * qq + idxx);

    const int bm = bid / nt, bn = bid % nt;
    const long m0 = (long)bm * 256;
    const int  n0 = bn * 256;
    const int wr = wave >> 2, wc = wave & 3;      // 2 x 4 wave grid
    const int lr = lane & 15, lg = lane >> 4;
    const int crow   = lane >> 3;
    const int ccol_s = ((lane & 7) ^ crow) * 8;   // swizzled global col
    const int swz    = (lr & 7) * 8;

    f32x4 acc[8][4] = {};

    auto stage = [&](int buf, int k0) {
#pragma unroll
        for (int p = 0; p < 4; ++p) {
            const int i = p * 8 + wave;           // chunk 0..31 (8 rows each)
            const int row = i * 8 + crow;
            GLDS(A + (m0 + row) * (long)K + k0 + ccol_s, &As[buf][i * 512]);
            GLDS(W + (long)(n0 + row) * K + k0 + ccol_s, &Bs[buf][i * 512]);
        }
    };

    auto compute = [&](int buf) {
        bf16x8 bfr[2][4];                          // [kk][fn], constant-indexed
#pragma unroll
        for (int kk2 = 0; kk2 < 2; ++kk2)
#pragma unroll
            for (int fn = 0; fn < 4; ++fn)
                bfr[kk2][fn] = *reinterpret_cast<const bf16x8*>(
                    &Bs[buf][(wc * 64 + fn * 16 + lr) * 64 + ((kk2 * 32 + lg * 8) ^ swz)]);
        bf16x8 aq[2][2], an[2][2];                 // quadrant double-buffer [fmpar][kk]
#pragma unroll
        for (int p = 0; p < 2; ++p)
#pragma unroll
            for (int kk2 = 0; kk2 < 2; ++kk2)
                aq[p][kk2] = *reinterpret_cast<const bf16x8*>(
                    &As[buf][(wr * 128 + p * 16 + lr) * 64 + ((kk2 * 32 + lg * 8) ^ swz)]);
#pragma unroll
        for (int q = 0; q < 4; ++q) {
            bf16x8 (&cur)[2][2] = (q & 1) ? an : aq;
            bf16x8 (&nxt)[2][2] = (q & 1) ? aq : an;
            if (q < 3) {
#pragma unroll
                for (int p = 0; p < 2; ++p)
#pragma unroll
                    for (int kk2 = 0; kk2 < 2; ++kk2)
                        nxt[p][kk2] = *reinterpret_cast<const bf16x8*>(
                            &As[buf][(wr * 128 + (2 * (q + 1) + p) * 16 + lr) * 64 + ((kk2 * 32 + lg * 8) ^ swz)]);
            }
            __builtin_amdgcn_s_setprio(1);
#pragma unroll
            for (int p = 0; p < 2; ++p)
#pragma unroll
                for (int kk2 = 0; kk2 < 2; ++kk2)
#pragma unroll
                    for (int fn = 0; fn < 4; ++fn)
                        acc[2 * q + p][fn] = MFMA(cur[p][kk2], bfr[kk2][fn], acc[2 * q + p][fn], 0, 0, 0);
            __builtin_amdgcn_s_setprio(0);
        }
    };

    const int nk = K >> 6;                        // 4 or 16
    stage(0, 0);
    stage(1, 64);
    int k = 128;
    for (int t = 0; t < nk - 1; ++t) {
        asm volatile("s_waitcnt vmcnt(8)" ::: "memory");   // tile t landed
        __builtin_amdgcn_s_barrier();
        __builtin_amdgcn_sched_barrier(0);
        compute(t & 1);
        __builtin_amdgcn_s_barrier();                       // buf t&1 free
        __builtin_amdgcn_sched_barrier(0);
        if (t + 2 < nk) {
            stage(t & 1, k); k += 64;
            __builtin_amdgcn_sched_barrier(0);
        }
    }
    asm volatile("s_waitcnt vmcnt(0)" ::: "memory");
    __builtin_amdgcn_s_barrier();
    __builtin_amdgcn_sched_barrier(0);
    compute((nk - 1) & 1);

    if constexpr (EPI == 1) {
        // ---- proj epilogue with fused LN2: x2 -> outf(f32), LN(x2) -> h2o(bf16)
        __shared__ float red[2][256][4];
        float g2c[4], b2c[4];
#pragma unroll
        for (int fn = 0; fn < 4; ++fn) {
            const int n = wc * 64 + fn * 16 + lr;          // n0 == 0 (nt==1)
            g2c[fn] = g2[n]; b2c[fn] = b2[n];
        }
#pragma unroll
        for (int fm = 0; fm < 8; ++fm) {
#pragma unroll
            for (int r = 0; r < 4; ++r) {
                const long m = m0 + wr * 128 + fm * 16 + lg * 4 + r;
                float s = 0.f, s2 = 0.f;
#pragma unroll
                for (int fn = 0; fn < 4; ++fn) {
                    const int n = wc * 64 + fn * 16 + lr;
                    const float x2 = acc[fm][fn][r] + bias[n] + res[m * 256 + n];
                    acc[fm][fn][r] = x2;
                    outf[m * 256 + n] = x2;
                    s += x2; s2 += x2 * x2;
                }
#pragma unroll
                for (int d = 1; d < 16; d <<= 1) { s += __shfl_xor(s, d); s2 += __shfl_xor(s2, d); }
                if (lr == 0) {
                    const int tok = wr * 128 + fm * 16 + lg * 4 + r;
                    red[0][tok][wc] = s; red[1][tok][wc] = s2;
                }
            }
        }
        __syncthreads();
#pragma unroll
        for (int fm = 0; fm < 8; ++fm) {
#pragma unroll
            for (int r = 0; r < 4; ++r) {
                const int tok = wr * 128 + fm * 16 + lg * 4 + r;
                const float s  = red[0][tok][0] + red[0][tok][1] + red[0][tok][2] + red[0][tok][3];
                const float q  = red[1][tok][0] + red[1][tok][1] + red[1][tok][2] + red[1][tok][3];
                const float mu = s * 0.00390625f;
                const float rs = rsqrtf(q * 0.00390625f - mu * mu + 1e-5f);
                const long m = m0 + tok;
#pragma unroll
                for (int fn = 0; fn < 4; ++fn) {
                    const int n = wc * 64 + fn * 16 + lr;
                    h2o[m * 256 + n] = f2b((acc[fm][fn][r] - mu) * rs * g2c[fn] + b2c[fn]);
                }
            }
        }
    } else {
#pragma unroll
        for (int fm = 0; fm < 8; ++fm) {
#pragma unroll
            for (int r = 0; r < 4; ++r) {
                const long m = m0 + wr * 128 + fm * 16 + lg * 4 + r;
                size_t mpart = 0;
                if (EPI == 0) {                   // hoisted m-decomposition (global row)
                    const int gm = (int)(m + moff);
                    const int b = gm / 50176;
                    const int rem = gm % 50176;
                    const int y = rem / 224, x = rem % 224;
                    const int win = (b * 32 + y / 7) * 32 + x / 7;
                    const int pos = (y % 7) * 7 + (x % 7);
                    mpart = (size_t)win * 12544 + (size_t)pos * 32;
                }
#pragma unroll
                for (int fn = 0; fn < 4; ++fn) {
                    const int n = n0 + wc * 64 + fn * 16 + lr;
                    const float v = acc[fm][fn][r];
                    if (EPI == 0) {
                        const int sec = n >> 8, hd = (n >> 5) & 7, d = n & 31;
                        const float sc = (sec == 0) ? 0.17677669529663687f : 1.0f;
                        outb[sec * QK_ELEMS + mpart + hd * 1568 + d] = f2b((v + bias[n]) * sc);
                    } else if (EPI == 2) {
                        const float t = v + bias[n];
                        const float s = t * (1.5957691216f + 0.07135481627f * t * t);
                        const float g = t * __builtin_amdgcn_rcpf(1.0f + __expf(-s));
                        outb[m * 1024 + n] = f2b(g);
                    } else {
                        outf[m * 256 + n] += v + bias[n];
                    }
                }
            }
        }
    }
}

// ---------------------------------------------------------------------------
// LayerNorm over C=256, f32 in -> bf16 out. 1 wave per token, 4 tokens/block.
// ---------------------------------------------------------------------------
__global__ __launch_bounds__(256)
void layernorm_k(const float* __restrict__ in, const float* __restrict__ g,
                 const float* __restrict__ bb, u16* __restrict__ out)
{
    const int token = blockIdx.x * 4 + (threadIdx.x >> 6);
    const int lane = threadIdx.x & 63;
    const float4 v = *reinterpret_cast<const float4*>(in + (size_t)token * 256 + lane * 4);
    float s  = v.x + v.y + v.z + v.w;
    float s2 = v.x * v.x + v.y * v.y + v.z * v.z + v.w * v.w;
#pragma unroll
    for (int m = 1; m < 64; m <<= 1) { s += __shfl_xor(s, m); s2 += __shfl_xor(s2, m); }
    const float mu  = s * (1.0f / 256.0f);
    const float var = s2 * (1.0f / 256.0f) - mu * mu;
    const float rs  = rsqrtf(var + 1e-5f);
    const float4 gv = *reinterpret_cast<const float4*>(g + lane * 4);
    const float4 bv = *reinterpret_cast<const float4*>(bb + lane * 4);
    ushort4 o;
    o.x = f2b((v.x - mu) * rs * gv.x + bv.x);
    o.y = f2b((v.y - mu) * rs * gv.y + bv.y);
    o.z = f2b((v.z - mu) * rs * gv.z + bv.z);
    o.w = f2b((v.w - mu) * rs * gv.w + bv.w);
    *reinterpret_cast<ushort4*>(out + (size_t)token * 256 + lane * 4) = o;
}

// ---------------------------------------------------------------------------
// Window attention: 1 wave per (window, head). Q pre-scaled. N=49 padded to 64.
// ---------------------------------------------------------------------------
__global__ __launch_bounds__(256)
void attn_win(const u16* __restrict__ qkv, const float* __restrict__ biasF,
              u16* __restrict__ outb, int pair0)
{
    __shared__ u16 plds[4][64 * 72];
    __shared__ u16 vlds[4][32 * 72];
    const int wave = threadIdx.x >> 6, lane = threadIdx.x & 63;
    const int pair = pair0 + blockIdx.x * 4 + wave;
    const int head = pair & 7, win = pair >> 3;
    const int lr = lane & 15, lg = lane >> 4;

    const u16* Q  = qkv + (size_t)pair * 1568;
    const u16* Kp = qkv + QK_ELEMS + (size_t)pair * 1568;
    const u16* Vp = qkv + 2 * QK_ELEMS + (size_t)pair * 1568;

    // ---- stage V^T into LDS (zero the pad columns pos=49..63 first) ----
    u16* vl = &vlds[wave][0];
#pragma unroll
    for (int it = 0; it < 8; ++it) {
        const int idx = it * 64 + lane;            // 480 pad elems: 32 d x 15 pos
        if (idx < 480) vl[(idx / 15) * 72 + 49 + idx % 15] = 0;
    }
#pragma unroll
    for (int it = 0; it < 4; ++it) {
        const int idx = it * 64 + lane;            // 196 groups of 8 elems
        if (idx < 196) {
            const int pos = idx >> 2, dc = idx & 3;
            const uint4 vv = *reinterpret_cast<const uint4*>(Vp + pos * 32 + dc * 8);
            u16* dst = vl + (dc * 8) * 72 + pos;
            dst[0 * 72] = (u16)vv.x;  dst[1 * 72] = (u16)(vv.x >> 16);
            dst[2 * 72] = (u16)vv.y;  dst[3 * 72] = (u16)(vv.y >> 16);
            dst[4 * 72] = (u16)vv.z;  dst[5 * 72] = (u16)(vv.z >> 16);
            dst[6 * 72] = (u16)vv.w;  dst[7 * 72] = (u16)(vv.w >> 16);
        }
    }

    // ---- QK^T ----
    bf16x8 qf[4], kf[4];
#pragma unroll
    for (int f = 0; f < 4; ++f) {
        int n = f * 16 + lr; n = n > 48 ? 48 : n;
        qf[f] = *reinterpret_cast<const bf16x8*>(Q  + n * 32 + lg * 8);
        kf[f] = *reinterpret_cast<const bf16x8*>(Kp + n * 32 + lg * 8);
    }
    f32x4 s[4][4] = {};
#pragma unroll
    for (int fm = 0; fm < 4; ++fm)
#pragma unroll
        for (int fn = 0; fn < 4; ++fn)
            s[fm][fn] = MFMA(qf[fm], kf[fn], s[fm][fn], 0, 0, 0);

    // ---- softmax (wave-parallel, 16-lane-group reduce) ----
    const float* bh = biasF + head * 2401;
    u16* pl = &plds[wave][0];
#pragma unroll
    for (int fm = 0; fm < 4; ++fm) {
#pragma unroll
        for (int r = 0; r < 4; ++r) {
            const int row = fm * 16 + lg * 4 + r;
            const int brow = row > 48 ? 48 : row;
            float v[4];
#pragma unroll
            for (int fn = 0; fn < 4; ++fn) {
                const int col = fn * 16 + lr;
                const float bval = bh[brow * 49 + (col > 48 ? 48 : col)];
                v[fn] = (col > 48) ? -3.0e38f : (s[fm][fn][r] + bval);
            }
            float mx = fmaxf(fmaxf(v[0], v[1]), fmaxf(v[2], v[3]));
#pragma unroll
            for (int d = 1; d < 16; d <<= 1) mx = fmaxf(mx, __shfl_xor(mx, d));
            float p[4], sum = 0.f;
#pragma unroll
            for (int fn = 0; fn < 4; ++fn) {
                const int col = fn * 16 + lr;
                p[fn] = (col <= 48) ? __expf(v[fn] - mx) : 0.f;
                sum += p[fn];
            }
#pragma unroll
            for (int d = 1; d < 16; d <<= 1) sum += __shfl_xor(sum, d);
            const float rinv = __builtin_amdgcn_rcpf(sum);
#pragma unroll
            for (int fn = 0; fn < 4; ++fn)
                pl[row * 72 + fn * 16 + lr] = f2b(p[fn] * rinv);
        }
    }
    __syncthreads();

    // ---- PV ----
    f32x4 o[4][2] = {};
#pragma unroll
    for (int kc = 0; kc < 2; ++kc) {
        bf16x8 vf[2];
#pragma unroll
        for (int f2 = 0; f2 < 2; ++f2)
            vf[f2] = *reinterpret_cast<const bf16x8*>(vl + (f2 * 16 + lr) * 72 + kc * 32 + lg * 8);
#pragma unroll
        for (int fm = 0; fm < 4; ++fm) {
            const bf16x8 pa = *reinterpret_cast<const bf16x8*>(pl + (fm * 16 + lr) * 72 + kc * 32 + lg * 8);
#pragma unroll
            for (int f2 = 0; f2 < 2; ++f2)
                o[fm][f2] = MFMA(pa, vf[f2], o[fm][f2], 0, 0, 0);
        }
    }

    // ---- window-reverse store ----
    const int b = win >> 10, rem = win & 1023, wy = rem >> 5, wx = rem & 31;
#pragma unroll
    for (int fm = 0; fm < 4; ++fm) {
#pragma unroll
        for (int r = 0; r < 4; ++r) {
            const int tok = fm * 16 + lg * 4 + r;
            if (tok > 48) continue;
            const int y = wy * 7 + tok / 7, xx = wx * 7 + tok % 7;
            const size_t mrow = ((size_t)(b * 224 + y)) * 224 + xx;
#pragma unroll
            for (int f2 = 0; f2 < 2; ++f2)
                outb[mrow * 256 + head * 32 + f2 * 16 + lr] = f2b(o[fm][f2][r]);
        }
    }
}

// ---------------------------------------------------------------------------
// Helpers
// ---------------------------------------------------------------------------
__global__ __launch_bounds__(256)
void cvt_w(const float* __restrict__ qw, const float* __restrict__ pw,
           const float* __restrict__ f1, const float* __restrict__ f2,
           u16* __restrict__ outw)
{
    const int t = blockIdx.x * 256 + threadIdx.x;  // 786432 total
    float v;
    if (t < 196608) v = qw[t];
    else if (t < 262144) v = pw[t - 196608];
    else if (t < 524288) v = f1[t - 262144];
    else v = f2[t - 524288];
    outw[t] = f2b(v);
}

__global__ __launch_bounds__(256)
void bias_pre(const float* __restrict__ btab, const int* __restrict__ relidx,
              float* __restrict__ biasF)
{
    const int t = blockIdx.x * 256 + threadIdx.x;
    if (t >= 19208) return;
    const int head = t / 2401, ij = t % 2401;
    biasF[t] = btab[relidx[ij] * 8 + head];
}

// ---------------------------------------------------------------------------
extern "C" void kernel_launch(void* const* d_in, const int* in_sizes, int n_in,
                              void* d_out, int out_size, void* d_ws, size_t ws_size,
                              hipStream_t stream)
{
    const float* x      = (const float*)d_in[0];
    const float* n1g    = (const float*)d_in[1];
    const float* n1b    = (const float*)d_in[2];
    const float* qkv_w  = (const float*)d_in[3];
    const float* qkv_b  = (const float*)d_in[4];
    const float* btab   = (const float*)d_in[5];
    const float* proj_w = (const float*)d_in[6];
    const float* proj_b = (const float*)d_in[7];
    const float* n2g    = (const float*)d_in[8];
    const float* n2b    = (const float*)d_in[9];
    const float* fc1_w  = (const float*)d_in[10];
    const float* fc1_b  = (const float*)d_in[11];
    const float* fc2_w  = (const float*)d_in[12];
    const float* fc2_b  = (const float*)d_in[13];
    const int*   relidx = (const int*)d_in[14];
    float* out = (float*)d_out;

    // workspace layout:
    //  [0, 1572864)                    : bf16 weights
    //  [1572864, 1649696)              : bias_full f32 (8x49x49)
    //  [1650688, +102760448)           : A region (bf16 token x 256): h / attn_out / h2
    //  [104411136, ...)                : R region: Q|K|V (308.3 MB), reused as MLP hidden
    char* ws = (char*)d_ws;
    u16*   wbf   = (u16*)ws;
    float* biasF = (float*)(ws + 1572864);
    u16*   hbuf  = (u16*)(ws + 1650688);
    u16*   rbuf  = (u16*)(ws + 1650688 + 102760448);
    const size_t r_avail = ws_size - (1650688 + 102760448);

    const u16* Wq  = wbf;
    const u16* Wp  = wbf + 196608;
    const u16* Wf1 = wbf + 262144;
    const u16* Wf2 = wbf + 524288;

    cvt_w<<<3072, 256, 0, stream>>>(qkv_w, proj_w, fc1_w, fc2_w, wbf);
    bias_pre<<<76, 256, 0, stream>>>(btab, relidx, biasF);
    layernorm_k<<<50176, 256, 0, stream>>>(x, n1g, n1b, hbuf);

    // Per-image QKV -> attention (qkv chunk 77 MB stays L3-resident)
    for (int b = 0; b < 4; ++b) {
        gemm256<0><<<588, 512, 0, stream>>>(hbuf + (size_t)b * 50176 * 256, Wq, qkv_b,
                                            3, 256, (long)b * 50176,
                                            rbuf, nullptr, nullptr, nullptr, nullptr, nullptr);
        attn_win<<<2048, 256, 0, stream>>>(rbuf, biasF, hbuf, b * 8192);
    }

    // proj + residual -> out (f32), fused LN2 -> hbuf (bf16, in-place over attn-out)
    gemm256<1><<<784, 512, 0, stream>>>(hbuf, Wp, proj_b, 1, 256, 0,
                                        nullptr, out, x, n2g, n2b, hbuf);

    // MLP chunked at 100352 rows (hidden chunk ~205 MB, mostly L3-resident)
    long rows_per = 100352;
    if ((long)(r_avail / 2048) < rows_per) rows_per = 50176;
    for (long r0 = 0; r0 < TOKENS; r0 += rows_per) {
        const long rows = (TOKENS - r0 < rows_per) ? (TOKENS - r0) : rows_per;
        gemm256<2><<<(int)((rows / 256) * 4), 512, 0, stream>>>(
            hbuf + r0 * 256, Wf1, fc1_b, 4, 256, 0, rbuf, nullptr, nullptr, nullptr, nullptr, nullptr);
        gemm256<3><<<(int)(rows / 256), 512, 0, stream>>>(
            rbuf, Wf2, fc2_b, 1, 1024, 0, nullptr, out + r0 * 256, nullptr, nullptr, nullptr, nullptr);
    }
}

// Round 9
// 1108.461 us; speedup vs baseline: 1.0753x; 1.0753x over previous
//
#include <hip/hip_runtime.h>

typedef unsigned short u16;
typedef __bf16 bf16x8 __attribute__((ext_vector_type(8)));
typedef float f32x4 __attribute__((ext_vector_type(4)));

#define TOKENS 200704
#define QK_ELEMS 51380224UL   // 32768 pairs * 49 * 32 (each of Q,K,V)

__device__ __forceinline__ u16 f2b(float f) {
    __bf16 h = (__bf16)f;                 // hw v_cvt (RTNE)
    return __builtin_bit_cast(u16, h);
}

#define GLDS(g, l) __builtin_amdgcn_global_load_lds( \
    (const __attribute__((address_space(1))) void*)(g), \
    (__attribute__((address_space(3))) void*)(l), 16, 0, 0)

#define MFMA __builtin_amdgcn_mfma_f32_16x16x32_bf16

// ---------------------------------------------------------------------------
// GEMM: C[m,n] = sum_k A[m,k]*W[n,k].  Tile BM x BN = (WR*64) x (WC*64),
// 8 waves (WR x WC grid of 64x64 wave-tiles, acc[4][4] = 64 regs -> fits
// 4 waves/SIMD), BK=32, double-buffered 48 KB LDS -> 2 blocks/CU,
// 16 waves/CU (2x R8 occupancy). Counted-vmcnt pipeline: stage(t+2) issued
// after compute(t)'s barrier; gate vmcnt(3) = tile t+1's 3 loads outstanding.
// 4-slot XOR swizzle: LDS[r][s] = global[r][s ^ ((r>>1)&3)] via pre-swizzled
// GLDS source col; ds_read slot = lg ^ ((lr>>1)&3). Conflict-free.
// EPI 0: qkv (+bias, q pre-scaled) -> (pair*49+pos)*32+d for Q,K,V
// EPI 1: proj: x2 = v+bias+res -> outf(f32) AND fused LN2 -> h2o(bf16)  [needs WC=4]
// EPI 2: fc1 (+bias, GELU -> bf16)   EPI 3: fc2 (+bias, outf +=)
// ---------------------------------------------------------------------------
template<int EPI, int WR, int WC>
__global__ __launch_bounds__(512, 4)
void gemm_t(const u16* __restrict__ A, const u16* __restrict__ W,
            const float* __restrict__ bias, int nt, int K,
            u16* __restrict__ outb, float* __restrict__ outf,
            const float* __restrict__ res,
            const float* __restrict__ g2, const float* __restrict__ b2,
            u16* __restrict__ h2o)
{
    constexpr int BM = WR * 64, BN = WC * 64;
    constexpr int ACH = BM / 16;            // A chunks (16 rows each)
    constexpr int TCH = (BM + BN) / 16;     // 24 total chunks
    __shared__ u16 As[2][BM * 32];
    __shared__ u16 Bs[2][BN * 32];
    __shared__ float red[EPI == 1 ? 2 * 128 * 4 : 1];

    const int tid  = threadIdx.x;
    const int wave = tid >> 6, lane = tid & 63;

    // bijective XCD-aware block swizzle (m204)
    const int nwg = gridDim.x, bidO = blockIdx.x;
    const int qq = nwg >> 3, rr = nwg & 7;
    const int xcd = bidO & 7, idxx = bidO >> 3;
    const int bid = (xcd < rr) ? (xcd * (qq + 1) + idxx)
                               : (rr * (qq + 1) + (xcd - rr) * qq + idxx);

    const int bm = bid / nt, bn = bid % nt;
    const long m0 = (long)bm * BM;
    const int  n0 = bn * BN;
    const int wr = wave / WC, wc = wave % WC;
    const int lr = lane & 15, lg = lane >> 4;
    // GLDS source col pre-swizzle: lane covers row (lane>>2), slot (lane&3)
    const int ccol_s = (((lane & 3) ^ ((lane >> 3) & 3)) * 8);
    // ds_read slot swizzle
    const int swzr = (lg ^ ((lr >> 1) & 3)) * 8;

    f32x4 acc[4][4] = {};

    auto stage = [&](int buf, int k0) {
#pragma unroll
        for (int p = 0; p < TCH / 8; ++p) {        // 3 GLDS per wave
            const int q = p * 8 + wave;
            const int rq = (q < ACH) ? q : q - ACH;
            const int row = rq * 16 + (lane >> 2);
            if (q < ACH)
                GLDS(A + (m0 + row) * (long)K + k0 + ccol_s, &As[buf][rq * 512]);
            else
                GLDS(W + (long)(n0 + row) * K + k0 + ccol_s, &Bs[buf][rq * 512]);
        }
    };

    auto compute = [&](int buf) {
        bf16x8 af[4], bfr[4];
#pragma unroll
        for (int fm = 0; fm < 4; ++fm)
            af[fm] = *reinterpret_cast<const bf16x8*>(
                &As[buf][(wr * 64 + fm * 16 + lr) * 32 + swzr]);
#pragma unroll
        for (int fn = 0; fn < 4; ++fn)
            bfr[fn] = *reinterpret_cast<const bf16x8*>(
                &Bs[buf][(wc * 64 + fn * 16 + lr) * 32 + swzr]);
        __builtin_amdgcn_s_setprio(1);
#pragma unroll
        for (int fm = 0; fm < 4; ++fm)
#pragma unroll
            for (int fn = 0; fn < 4; ++fn)
                acc[fm][fn] = MFMA(af[fm], bfr[fn], acc[fm][fn], 0, 0, 0);
        __builtin_amdgcn_s_setprio(0);
    };

    const int nk = K >> 5;                  // 8 (K=256) or 32 (K=1024)
    stage(0, 0);
    stage(1, 32);
    int k = 64;
    for (int t = 0; t < nk; ++t) {
        if (t == nk - 1) asm volatile("s_waitcnt vmcnt(0)" ::: "memory");
        else             asm volatile("s_waitcnt vmcnt(3)" ::: "memory");
        __builtin_amdgcn_s_barrier();
        __builtin_amdgcn_sched_barrier(0);
        compute(t & 1);
        __builtin_amdgcn_s_barrier();
        __builtin_amdgcn_sched_barrier(0);
        if (t + 2 < nk) {
            stage(t & 1, k); k += 32;
            __builtin_amdgcn_sched_barrier(0);
        }
    }

    if constexpr (EPI == 1) {
        // proj + residual -> outf (f32); fused LN2 -> h2o (bf16). BM=128, WC=4.
        float g2c[4], b2c[4];
#pragma unroll
        for (int fn = 0; fn < 4; ++fn) {
            const int n = wc * 64 + fn * 16 + lr;          // n0 == 0 (nt==1)
            g2c[fn] = g2[n]; b2c[fn] = b2[n];
        }
#pragma unroll
        for (int fm = 0; fm < 4; ++fm) {
#pragma unroll
            for (int r = 0; r < 4; ++r) {
                const long m = m0 + wr * 64 + fm * 16 + lg * 4 + r;
                float s = 0.f, s2 = 0.f;
#pragma unroll
                for (int fn = 0; fn < 4; ++fn) {
                    const int n = wc * 64 + fn * 16 + lr;
                    const float x2 = acc[fm][fn][r] + bias[n] + res[m * 256 + n];
                    acc[fm][fn][r] = x2;
                    outf[m * 256 + n] = x2;
                    s += x2; s2 += x2 * x2;
                }
#pragma unroll
                for (int d = 1; d < 16; d <<= 1) { s += __shfl_xor(s, d); s2 += __shfl_xor(s2, d); }
                if (lr == 0) {
                    const int tok = wr * 64 + fm * 16 + lg * 4 + r;
                    red[(0 * 128 + tok) * 4 + wc] = s;
                    red[(1 * 128 + tok) * 4 + wc] = s2;
                }
            }
        }
        __syncthreads();
#pragma unroll
        for (int fm = 0; fm < 4; ++fm) {
#pragma unroll
            for (int r = 0; r < 4; ++r) {
                const int tok = wr * 64 + fm * 16 + lg * 4 + r;
                const float s = red[(0 * 128 + tok) * 4 + 0] + red[(0 * 128 + tok) * 4 + 1]
                              + red[(0 * 128 + tok) * 4 + 2] + red[(0 * 128 + tok) * 4 + 3];
                const float q = red[(1 * 128 + tok) * 4 + 0] + red[(1 * 128 + tok) * 4 + 1]
                              + red[(1 * 128 + tok) * 4 + 2] + red[(1 * 128 + tok) * 4 + 3];
                const float mu = s * 0.00390625f;
                const float rs = rsqrtf(q * 0.00390625f - mu * mu + 1e-5f);
                const long m = m0 + tok;
#pragma unroll
                for (int fn = 0; fn < 4; ++fn) {
                    const int n = wc * 64 + fn * 16 + lr;
                    h2o[m * 256 + n] = f2b((acc[fm][fn][r] - mu) * rs * g2c[fn] + b2c[fn]);
                }
            }
        }
    } else {
#pragma unroll
        for (int fm = 0; fm < 4; ++fm) {
#pragma unroll
            for (int r = 0; r < 4; ++r) {
                const long m = m0 + wr * 64 + fm * 16 + lg * 4 + r;
                size_t mpart = 0;
                if (EPI == 0) {                   // hoisted m-decomposition
                    const int gm = (int)m;
                    const int b = gm / 50176;
                    const int rem = gm % 50176;
                    const int y = rem / 224, x = rem % 224;
                    const int win = (b * 32 + y / 7) * 32 + x / 7;
                    const int pos = (y % 7) * 7 + (x % 7);
                    mpart = (size_t)win * 12544 + (size_t)pos * 32;
                }
#pragma unroll
                for (int fn = 0; fn < 4; ++fn) {
                    const int n = n0 + wc * 64 + fn * 16 + lr;
                    const float v = acc[fm][fn][r];
                    if (EPI == 0) {
                        const int sec = n >> 8, hd = (n >> 5) & 7, d = n & 31;
                        const float sc = (sec == 0) ? 0.17677669529663687f : 1.0f;
                        outb[sec * QK_ELEMS + mpart + hd * 1568 + d] = f2b((v + bias[n]) * sc);
                    } else if (EPI == 2) {
                        const float t = v + bias[n];
                        const float s = t * (1.5957691216f + 0.07135481627f * t * t);
                        const float g = t * __builtin_amdgcn_rcpf(1.0f + __expf(-s));
                        outb[m * 1024 + n] = f2b(g);
                    } else {
                        outf[m * 256 + n] += v + bias[n];
                    }
                }
            }
        }
    }
}

// ---------------------------------------------------------------------------
// LayerNorm over C=256, f32 in -> bf16 out. 1 wave per token, 4 tokens/block.
// ---------------------------------------------------------------------------
__global__ __launch_bounds__(256)
void layernorm_k(const float* __restrict__ in, const float* __restrict__ g,
                 const float* __restrict__ bb, u16* __restrict__ out)
{
    const int token = blockIdx.x * 4 + (threadIdx.x >> 6);
    const int lane = threadIdx.x & 63;
    const float4 v = *reinterpret_cast<const float4*>(in + (size_t)token * 256 + lane * 4);
    float s  = v.x + v.y + v.z + v.w;
    float s2 = v.x * v.x + v.y * v.y + v.z * v.z + v.w * v.w;
#pragma unroll
    for (int m = 1; m < 64; m <<= 1) { s += __shfl_xor(s, m); s2 += __shfl_xor(s2, m); }
    const float mu  = s * (1.0f / 256.0f);
    const float var = s2 * (1.0f / 256.0f) - mu * mu;
    const float rs  = rsqrtf(var + 1e-5f);
    const float4 gv = *reinterpret_cast<const float4*>(g + lane * 4);
    const float4 bv = *reinterpret_cast<const float4*>(bb + lane * 4);
    ushort4 o;
    o.x = f2b((v.x - mu) * rs * gv.x + bv.x);
    o.y = f2b((v.y - mu) * rs * gv.y + bv.y);
    o.z = f2b((v.z - mu) * rs * gv.z + bv.z);
    o.w = f2b((v.w - mu) * rs * gv.w + bv.w);
    *reinterpret_cast<ushort4*>(out + (size_t)token * 256 + lane * 4) = o;
}

// ---------------------------------------------------------------------------
// Window attention: 1 wave per (window, head). Q pre-scaled. N=49 padded to 64.
// ---------------------------------------------------------------------------
__global__ __launch_bounds__(256)
void attn_win(const u16* __restrict__ qkv, const float* __restrict__ biasF,
              u16* __restrict__ outb)
{
    __shared__ u16 plds[4][64 * 72];
    __shared__ u16 vlds[4][32 * 72];
    const int wave = threadIdx.x >> 6, lane = threadIdx.x & 63;
    const int pair = blockIdx.x * 4 + wave;
    const int head = pair & 7, win = pair >> 3;
    const int lr = lane & 15, lg = lane >> 4;

    const u16* Q  = qkv + (size_t)pair * 1568;
    const u16* Kp = qkv + QK_ELEMS + (size_t)pair * 1568;
    const u16* Vp = qkv + 2 * QK_ELEMS + (size_t)pair * 1568;

    // ---- stage V^T into LDS (zero the pad columns pos=49..63 first) ----
    u16* vl = &vlds[wave][0];
#pragma unroll
    for (int it = 0; it < 8; ++it) {
        const int idx = it * 64 + lane;            // 480 pad elems: 32 d x 15 pos
        if (idx < 480) vl[(idx / 15) * 72 + 49 + idx % 15] = 0;
    }
#pragma unroll
    for (int it = 0; it < 4; ++it) {
        const int idx = it * 64 + lane;            // 196 groups of 8 elems
        if (idx < 196) {
            const int pos = idx >> 2, dc = idx & 3;
            const uint4 vv = *reinterpret_cast<const uint4*>(Vp + pos * 32 + dc * 8);
            u16* dst = vl + (dc * 8) * 72 + pos;
            dst[0 * 72] = (u16)vv.x;  dst[1 * 72] = (u16)(vv.x >> 16);
            dst[2 * 72] = (u16)vv.y;  dst[3 * 72] = (u16)(vv.y >> 16);
            dst[4 * 72] = (u16)vv.z;  dst[5 * 72] = (u16)(vv.z >> 16);
            dst[6 * 72] = (u16)vv.w;  dst[7 * 72] = (u16)(vv.w >> 16);
        }
    }

    // ---- QK^T ----
    bf16x8 qf[4], kf[4];
#pragma unroll
    for (int f = 0; f < 4; ++f) {
        int n = f * 16 + lr; n = n > 48 ? 48 : n;
        qf[f] = *reinterpret_cast<const bf16x8*>(Q  + n * 32 + lg * 8);
        kf[f] = *reinterpret_cast<const bf16x8*>(Kp + n * 32 + lg * 8);
    }
    f32x4 s[4][4] = {};
#pragma unroll
    for (int fm = 0; fm < 4; ++fm)
#pragma unroll
        for (int fn = 0; fn < 4; ++fn)
            s[fm][fn] = MFMA(qf[fm], kf[fn], s[fm][fn], 0, 0, 0);

    // ---- softmax (wave-parallel, 16-lane-group reduce) ----
    const float* bh = biasF + head * 2401;
    u16* pl = &plds[wave][0];
#pragma unroll
    for (int fm = 0; fm < 4; ++fm) {
#pragma unroll
        for (int r = 0; r < 4; ++r) {
            const int row = fm * 16 + lg * 4 + r;
            const int brow = row > 48 ? 48 : row;
            float v[4];
#pragma unroll
            for (int fn = 0; fn < 4; ++fn) {
                const int col = fn * 16 + lr;
                const float bval = bh[brow * 49 + (col > 48 ? 48 : col)];
                v[fn] = (col > 48) ? -3.0e38f : (s[fm][fn][r] + bval);
            }
            float mx = fmaxf(fmaxf(v[0], v[1]), fmaxf(v[2], v[3]));
#pragma unroll
            for (int d = 1; d < 16; d <<= 1) mx = fmaxf(mx, __shfl_xor(mx, d));
            float p[4], sum = 0.f;
#pragma unroll
            for (int fn = 0; fn < 4; ++fn) {
                const int col = fn * 16 + lr;
                p[fn] = (col <= 48) ? __expf(v[fn] - mx) : 0.f;
                sum += p[fn];
            }
#pragma unroll
            for (int d = 1; d < 16; d <<= 1) sum += __shfl_xor(sum, d);
            const float rinv = __builtin_amdgcn_rcpf(sum);
#pragma unroll
            for (int fn = 0; fn < 4; ++fn)
                pl[row * 72 + fn * 16 + lr] = f2b(p[fn] * rinv);
        }
    }
    __syncthreads();

    // ---- PV ----
    f32x4 o[4][2] = {};
#pragma unroll
    for (int kc = 0; kc < 2; ++kc) {
        bf16x8 vf[2];
#pragma unroll
        for (int f2 = 0; f2 < 2; ++f2)
            vf[f2] = *reinterpret_cast<const bf16x8*>(vl + (f2 * 16 + lr) * 72 + kc * 32 + lg * 8);
#pragma unroll
        for (int fm = 0; fm < 4; ++fm) {
            const bf16x8 pa = *reinterpret_cast<const bf16x8*>(pl + (fm * 16 + lr) * 72 + kc * 32 + lg * 8);
#pragma unroll
            for (int f2 = 0; f2 < 2; ++f2)
                o[fm][f2] = MFMA(pa, vf[f2], o[fm][f2], 0, 0, 0);
        }
    }

    // ---- window-reverse store ----
    const int b = win >> 10, rem = win & 1023, wy = rem >> 5, wx = rem & 31;
#pragma unroll
    for (int fm = 0; fm < 4; ++fm) {
#pragma unroll
        for (int r = 0; r < 4; ++r) {
            const int tok = fm * 16 + lg * 4 + r;
            if (tok > 48) continue;
            const int y = wy * 7 + tok / 7, xx = wx * 7 + tok % 7;
            const size_t mrow = ((size_t)(b * 224 + y)) * 224 + xx;
#pragma unroll
            for (int f2 = 0; f2 < 2; ++f2)
                outb[mrow * 256 + head * 32 + f2 * 16 + lr] = f2b(o[fm][f2][r]);
        }
    }
}

// ---------------------------------------------------------------------------
// Helpers
// ---------------------------------------------------------------------------
__global__ __launch_bounds__(256)
void cvt_w(const float* __restrict__ qw, const float* __restrict__ pw,
           const float* __restrict__ f1, const float* __restrict__ f2,
           u16* __restrict__ outw)
{
    const int t = blockIdx.x * 256 + threadIdx.x;  // 786432 total
    float v;
    if (t < 196608) v = qw[t];
    else if (t < 262144) v = pw[t - 196608];
    else if (t < 524288) v = f1[t - 262144];
    else v = f2[t - 524288];
    outw[t] = f2b(v);
}

__global__ __launch_bounds__(256)
void bias_pre(const float* __restrict__ btab, const int* __restrict__ relidx,
              float* __restrict__ biasF)
{
    const int t = blockIdx.x * 256 + threadIdx.x;
    if (t >= 19208) return;
    const int head = t / 2401, ij = t % 2401;
    biasF[t] = btab[relidx[ij] * 8 + head];
}

// ---------------------------------------------------------------------------
extern "C" void kernel_launch(void* const* d_in, const int* in_sizes, int n_in,
                              void* d_out, int out_size, void* d_ws, size_t ws_size,
                              hipStream_t stream)
{
    const float* x      = (const float*)d_in[0];
    const float* n1g    = (const float*)d_in[1];
    const float* n1b    = (const float*)d_in[2];
    const float* qkv_w  = (const float*)d_in[3];
    const float* qkv_b  = (const float*)d_in[4];
    const float* btab   = (const float*)d_in[5];
    const float* proj_w = (const float*)d_in[6];
    const float* proj_b = (const float*)d_in[7];
    const float* n2g    = (const float*)d_in[8];
    const float* n2b    = (const float*)d_in[9];
    const float* fc1_w  = (const float*)d_in[10];
    const float* fc1_b  = (const float*)d_in[11];
    const float* fc2_w  = (const float*)d_in[12];
    const float* fc2_b  = (const float*)d_in[13];
    const int*   relidx = (const int*)d_in[14];
    float* out = (float*)d_out;

    // workspace layout:
    //  [0, 1572864)                    : bf16 weights
    //  [1572864, 1649696)              : bias_full f32 (8x49x49)
    //  [1650688, +102760448)           : A region (bf16 token x 256): h / attn_out / h2
    //  [104411136, ...)                : R region: Q|K|V (308.3 MB), reused as MLP hidden
    char* ws = (char*)d_ws;
    u16*   wbf   = (u16*)ws;
    float* biasF = (float*)(ws + 1572864);
    u16*   hbuf  = (u16*)(ws + 1650688);
    u16*   rbuf  = (u16*)(ws + 1650688 + 102760448);
    const size_t r_avail = ws_size - (1650688 + 102760448);

    const u16* Wq  = wbf;
    const u16* Wp  = wbf + 196608;
    const u16* Wf1 = wbf + 262144;
    const u16* Wf2 = wbf + 524288;

    cvt_w<<<3072, 256, 0, stream>>>(qkv_w, proj_w, fc1_w, fc2_w, wbf);
    bias_pre<<<76, 256, 0, stream>>>(btab, relidx, biasF);
    layernorm_k<<<50176, 256, 0, stream>>>(x, n1g, n1b, hbuf);

    // QKV projection: M=200704 (784 m-tiles of 256), N=768 (6 n-tiles of 128)
    gemm_t<0, 4, 2><<<784 * 6, 512, 0, stream>>>(hbuf, Wq, qkv_b, 6, 256,
                                                 rbuf, nullptr, nullptr, nullptr, nullptr, nullptr);
    // window attention
    attn_win<<<8192, 256, 0, stream>>>(rbuf, biasF, hbuf);

    // proj + residual -> out (f32), fused LN2 -> hbuf (bf16); BM=128, BN=256
    gemm_t<1, 2, 4><<<1568, 512, 0, stream>>>(hbuf, Wp, proj_b, 1, 256,
                                              nullptr, out, x, n2g, n2b, hbuf);

    // MLP chunked at 100352 rows (hidden chunk ~205 MB, mostly L3-resident)
    long rows_per = 100352;
    if ((long)(r_avail / 2048) < rows_per) rows_per = 50176;
    for (long r0 = 0; r0 < TOKENS; r0 += rows_per) {
        const long rows = (TOKENS - r0 < rows_per) ? (TOKENS - r0) : rows_per;
        gemm_t<2, 4, 2><<<(int)((rows / 256) * 8), 512, 0, stream>>>(
            hbuf + r0 * 256, Wf1, fc1_b, 8, 256, rbuf, nullptr, nullptr, nullptr, nullptr, nullptr);
        gemm_t<3, 4, 2><<<(int)((rows / 256) * 2), 512, 0, stream>>>(
            rbuf, Wf2, fc2_b, 2, 1024, nullptr, out + r0 * 256, nullptr, nullptr, nullptr, nullptr);
    }
}

// Round 10
// 1000.842 us; speedup vs baseline: 1.1909x; 1.1075x over previous
//
#include <hip/hip_runtime.h>

typedef unsigned short u16;
typedef __bf16 bf16x8 __attribute__((ext_vector_type(8)));
typedef float f32x4 __attribute__((ext_vector_type(4)));

#define TOKENS 200704
#define QK_ELEMS 51380224UL   // 32768 pairs * 49 * 32 (each of Q,K,V)

__device__ __forceinline__ u16 f2b(float f) {
    __bf16 h = (__bf16)f;                 // hw v_cvt (RTNE)
    return __builtin_bit_cast(u16, h);
}

#define GLDS(g, l) __builtin_amdgcn_global_load_lds( \
    (const __attribute__((address_space(1))) void*)(g), \
    (__attribute__((address_space(3))) void*)(l), 16, 0, 0)

#define MFMA __builtin_amdgcn_mfma_f32_16x16x32_bf16

// ---------------------------------------------------------------------------
// GEMM: C[m,n] = sum_k A[m,k]*W[n,k].  Tile BM x BN = (WR*64) x (WC*64),
// 8 waves (WR x WC grid of 64x64 wave-tiles, acc[4][4] = 64 regs), BK=32,
// double-buffered 48 KB LDS -> 2 blocks/CU, 16 waves/CU. Counted-vmcnt
// pipeline; 4-slot XOR swizzle (conflict-free, verified).
// EPI 0: qkv (+bias, q pre-scaled) -> (pair*49+pos)*32+d for Q,K,V
// EPI 1: proj: x2 = v+bias+res -> outf(f32) AND fused LN2 -> h2o(bf16)  [needs WC=4]
// EPI 2: fc1 (+bias, GELU -> bf16)   EPI 3: fc2 (+bias, outf +=)
// ---------------------------------------------------------------------------
template<int EPI, int WR, int WC>
__global__ __launch_bounds__(512, 4)
void gemm_t(const u16* __restrict__ A, const u16* __restrict__ W,
            const float* __restrict__ bias, int nt, int K,
            u16* __restrict__ outb, float* __restrict__ outf,
            const float* __restrict__ res,
            const float* __restrict__ g2, const float* __restrict__ b2,
            u16* __restrict__ h2o)
{
    constexpr int BM = WR * 64, BN = WC * 64;
    constexpr int ACH = BM / 16;            // A chunks (16 rows each)
    constexpr int TCH = (BM + BN) / 16;     // 24 total chunks
    __shared__ u16 As[2][BM * 32];
    __shared__ u16 Bs[2][BN * 32];
    __shared__ float red[EPI == 1 ? 2 * 128 * 4 : 1];

    const int tid  = threadIdx.x;
    const int wave = tid >> 6, lane = tid & 63;

    // bijective XCD-aware block swizzle (m204)
    const int nwg = gridDim.x, bidO = blockIdx.x;
    const int qq = nwg >> 3, rr = nwg & 7;
    const int xcd = bidO & 7, idxx = bidO >> 3;
    const int bid = (xcd < rr) ? (xcd * (qq + 1) + idxx)
                               : (rr * (qq + 1) + (xcd - rr) * qq + idxx);

    const int bm = bid / nt, bn = bid % nt;
    const long m0 = (long)bm * BM;
    const int  n0 = bn * BN;
    const int wr = wave / WC, wc = wave % WC;
    const int lr = lane & 15, lg = lane >> 4;
    const int ccol_s = (((lane & 3) ^ ((lane >> 3) & 3)) * 8);
    const int swzr = (lg ^ ((lr >> 1) & 3)) * 8;

    f32x4 acc[4][4] = {};

    auto stage = [&](int buf, int k0) {
#pragma unroll
        for (int p = 0; p < TCH / 8; ++p) {        // 3 GLDS per wave
            const int q = p * 8 + wave;
            const int rq = (q < ACH) ? q : q - ACH;
            const int row = rq * 16 + (lane >> 2);
            if (q < ACH)
                GLDS(A + (m0 + row) * (long)K + k0 + ccol_s, &As[buf][rq * 512]);
            else
                GLDS(W + (long)(n0 + row) * K + k0 + ccol_s, &Bs[buf][rq * 512]);
        }
    };

    auto compute = [&](int buf) {
        bf16x8 af[4], bfr[4];
#pragma unroll
        for (int fm = 0; fm < 4; ++fm)
            af[fm] = *reinterpret_cast<const bf16x8*>(
                &As[buf][(wr * 64 + fm * 16 + lr) * 32 + swzr]);
#pragma unroll
        for (int fn = 0; fn < 4; ++fn)
            bfr[fn] = *reinterpret_cast<const bf16x8*>(
                &Bs[buf][(wc * 64 + fn * 16 + lr) * 32 + swzr]);
        __builtin_amdgcn_s_setprio(1);
#pragma unroll
        for (int fm = 0; fm < 4; ++fm)
#pragma unroll
            for (int fn = 0; fn < 4; ++fn)
                acc[fm][fn] = MFMA(af[fm], bfr[fn], acc[fm][fn], 0, 0, 0);
        __builtin_amdgcn_s_setprio(0);
    };

    const int nk = K >> 5;                  // 8 (K=256) or 32 (K=1024)
    stage(0, 0);
    stage(1, 32);
    int k = 64;
    for (int t = 0; t < nk; ++t) {
        if (t == nk - 1) asm volatile("s_waitcnt vmcnt(0)" ::: "memory");
        else             asm volatile("s_waitcnt vmcnt(3)" ::: "memory");
        __builtin_amdgcn_s_barrier();
        __builtin_amdgcn_sched_barrier(0);
        compute(t & 1);
        __builtin_amdgcn_s_barrier();
        __builtin_amdgcn_sched_barrier(0);
        if (t + 2 < nk) {
            stage(t & 1, k); k += 32;
            __builtin_amdgcn_sched_barrier(0);
        }
    }

    if constexpr (EPI == 1) {
        // proj + residual -> outf (f32); fused LN2 -> h2o (bf16). BM=128, WC=4.
        float g2c[4], b2c[4];
#pragma unroll
        for (int fn = 0; fn < 4; ++fn) {
            const int n = wc * 64 + fn * 16 + lr;          // n0 == 0 (nt==1)
            g2c[fn] = g2[n]; b2c[fn] = b2[n];
        }
#pragma unroll
        for (int fm = 0; fm < 4; ++fm) {
#pragma unroll
            for (int r = 0; r < 4; ++r) {
                const long m = m0 + wr * 64 + fm * 16 + lg * 4 + r;
                float s = 0.f, s2 = 0.f;
#pragma unroll
                for (int fn = 0; fn < 4; ++fn) {
                    const int n = wc * 64 + fn * 16 + lr;
                    const float x2 = acc[fm][fn][r] + bias[n] + res[m * 256 + n];
                    acc[fm][fn][r] = x2;
                    outf[m * 256 + n] = x2;
                    s += x2; s2 += x2 * x2;
                }
#pragma unroll
                for (int d = 1; d < 16; d <<= 1) { s += __shfl_xor(s, d); s2 += __shfl_xor(s2, d); }
                if (lr == 0) {
                    const int tok = wr * 64 + fm * 16 + lg * 4 + r;
                    red[(0 * 128 + tok) * 4 + wc] = s;
                    red[(1 * 128 + tok) * 4 + wc] = s2;
                }
            }
        }
        __syncthreads();
#pragma unroll
        for (int fm = 0; fm < 4; ++fm) {
#pragma unroll
            for (int r = 0; r < 4; ++r) {
                const int tok = wr * 64 + fm * 16 + lg * 4 + r;
                const float s = red[(0 * 128 + tok) * 4 + 0] + red[(0 * 128 + tok) * 4 + 1]
                              + red[(0 * 128 + tok) * 4 + 2] + red[(0 * 128 + tok) * 4 + 3];
                const float q = red[(1 * 128 + tok) * 4 + 0] + red[(1 * 128 + tok) * 4 + 1]
                              + red[(1 * 128 + tok) * 4 + 2] + red[(1 * 128 + tok) * 4 + 3];
                const float mu = s * 0.00390625f;
                const float rs = rsqrtf(q * 0.00390625f - mu * mu + 1e-5f);
                const long m = m0 + tok;
#pragma unroll
                for (int fn = 0; fn < 4; ++fn) {
                    const int n = wc * 64 + fn * 16 + lr;
                    h2o[m * 256 + n] = f2b((acc[fm][fn][r] - mu) * rs * g2c[fn] + b2c[fn]);
                }
            }
        }
    } else {
#pragma unroll
        for (int fm = 0; fm < 4; ++fm) {
#pragma unroll
            for (int r = 0; r < 4; ++r) {
                const long m = m0 + wr * 64 + fm * 16 + lg * 4 + r;
                size_t mpart = 0;
                if (EPI == 0) {                   // hoisted m-decomposition
                    const int gm = (int)m;
                    const int b = gm / 50176;
                    const int rem = gm % 50176;
                    const int y = rem / 224, x = rem % 224;
                    const int win = (b * 32 + y / 7) * 32 + x / 7;
                    const int pos = (y % 7) * 7 + (x % 7);
                    mpart = (size_t)win * 12544 + (size_t)pos * 32;
                }
#pragma unroll
                for (int fn = 0; fn < 4; ++fn) {
                    const int n = n0 + wc * 64 + fn * 16 + lr;
                    const float v = acc[fm][fn][r];
                    if (EPI == 0) {
                        const int sec = n >> 8, hd = (n >> 5) & 7, d = n & 31;
                        const float sc = (sec == 0) ? 0.17677669529663687f : 1.0f;
                        outb[sec * QK_ELEMS + mpart + hd * 1568 + d] = f2b((v + bias[n]) * sc);
                    } else if (EPI == 2) {
                        const float t = v + bias[n];
                        const float s = t * (1.5957691216f + 0.07135481627f * t * t);
                        const float g = t * __builtin_amdgcn_rcpf(1.0f + __expf(-s));
                        outb[m * 1024 + n] = f2b(g);
                    } else {
                        outf[m * 256 + n] += v + bias[n];
                    }
                }
            }
        }
    }
}

// ---------------------------------------------------------------------------
// LayerNorm over C=256, f32 in -> bf16 out. 1 wave per token, 4 tokens/block.
// ---------------------------------------------------------------------------
__global__ __launch_bounds__(256)
void layernorm_k(const float* __restrict__ in, const float* __restrict__ g,
                 const float* __restrict__ bb, u16* __restrict__ out)
{
    const int token = blockIdx.x * 4 + (threadIdx.x >> 6);
    const int lane = threadIdx.x & 63;
    const float4 v = *reinterpret_cast<const float4*>(in + (size_t)token * 256 + lane * 4);
    float s  = v.x + v.y + v.z + v.w;
    float s2 = v.x * v.x + v.y * v.y + v.z * v.z + v.w * v.w;
#pragma unroll
    for (int m = 1; m < 64; m <<= 1) { s += __shfl_xor(s, m); s2 += __shfl_xor(s2, m); }
    const float mu  = s * (1.0f / 256.0f);
    const float var = s2 * (1.0f / 256.0f) - mu * mu;
    const float rs  = rsqrtf(var + 1e-5f);
    const float4 gv = *reinterpret_cast<const float4*>(g + lane * 4);
    const float4 bv = *reinterpret_cast<const float4*>(bb + lane * 4);
    ushort4 o;
    o.x = f2b((v.x - mu) * rs * gv.x + bv.x);
    o.y = f2b((v.y - mu) * rs * gv.y + bv.y);
    o.z = f2b((v.z - mu) * rs * gv.z + bv.z);
    o.w = f2b((v.w - mu) * rs * gv.w + bv.w);
    *reinterpret_cast<ushort4*>(out + (size_t)token * 256 + lane * 4) = o;
}

// ---------------------------------------------------------------------------
// Window attention: 1 wave per (window, head), fully wave-independent (no
// __syncthreads). Bias pre-baked in fragment layout (pads = -1e30). V staged
// via 4x global_load_lds into [2 dblk][64 pos][16 d] and consumed through
// ds_read_b64_tr_b16 (column-of-4x16-tile gather, offset:128 = +4 pos).
// ---------------------------------------------------------------------------
__global__ __launch_bounds__(256)
void attn_win(const u16* __restrict__ qkv, const float* __restrict__ biasF,
              u16* __restrict__ outb)
{
    __shared__ u16 plds[4][64 * 72];
    __shared__ u16 vlds[4][2048];
    const int wave = threadIdx.x >> 6, lane = threadIdx.x & 63;
    const int pair = blockIdx.x * 4 + wave;
    const int head = pair & 7, win = pair >> 3;
    const int lr = lane & 15, lg = lane >> 4;

    const u16* Q  = qkv + (size_t)pair * 1568;
    const u16* Kp = qkv + QK_ELEMS + (size_t)pair * 1568;
    const u16* Vp = qkv + 2 * QK_ELEMS + (size_t)pair * 1568;

    // ---- Q,K fragments (issued first = oldest vmcnt) ----
    bf16x8 qf[4], kf[4];
#pragma unroll
    for (int f = 0; f < 4; ++f) {
        int n = f * 16 + lr; n = n > 48 ? 48 : n;
        qf[f] = *reinterpret_cast<const bf16x8*>(Q  + n * 32 + lg * 8);
        kf[f] = *reinterpret_cast<const bf16x8*>(Kp + n * 32 + lg * 8);
    }

    // ---- V staging: 4x global_load_lds -> [db][pos][16] (pads zeroed later) ----
    u16* vl = &vlds[wave][0];
    {
        const int posh = lane >> 1, dsub = (lane & 1) * 8;
#pragma unroll
        for (int db = 0; db < 2; ++db)
#pragma unroll
            for (int half = 0; half < 2; ++half) {
                int pos = half * 32 + posh; if (pos > 48) pos = 48;   // clamp source
                GLDS(Vp + pos * 32 + db * 16 + dsub, vl + db * 1024 + half * 512);
            }
    }

    // ---- QK^T ----
    f32x4 s[4][4] = {};
#pragma unroll
    for (int fm = 0; fm < 4; ++fm)
#pragma unroll
        for (int fn = 0; fn < 4; ++fn)
            s[fm][fn] = MFMA(qf[fm], kf[fn], s[fm][fn], 0, 0, 0);

    // ---- softmax: bias fragments coalesced, pads pre-masked ----
    const float* bfh = biasF + head * 4096;        // 16 frags * 256 floats
    u16* pl = &plds[wave][0];
#pragma unroll
    for (int fm = 0; fm < 4; ++fm) {
        f32x4 bb[4];
#pragma unroll
        for (int fn = 0; fn < 4; ++fn)
            bb[fn] = *reinterpret_cast<const f32x4*>(bfh + ((fm * 4 + fn) << 8) + (lane << 2));
#pragma unroll
        for (int r = 0; r < 4; ++r) {
            const int row = fm * 16 + lg * 4 + r;
            float v0 = s[fm][0][r] + bb[0][r];
            float v1 = s[fm][1][r] + bb[1][r];
            float v2 = s[fm][2][r] + bb[2][r];
            float v3 = s[fm][3][r] + bb[3][r];
            float mx = fmaxf(fmaxf(v0, v1), fmaxf(v2, v3));
#pragma unroll
            for (int d = 1; d < 16; d <<= 1) mx = fmaxf(mx, __shfl_xor(mx, d));
            const float p0 = __expf(v0 - mx), p1 = __expf(v1 - mx);
            const float p2 = __expf(v2 - mx), p3 = __expf(v3 - mx);
            float sum = p0 + p1 + p2 + p3;
#pragma unroll
            for (int d = 1; d < 16; d <<= 1) sum += __shfl_xor(sum, d);
            const float rinv = __builtin_amdgcn_rcpf(sum);
            pl[row * 72 +  0 + lr] = f2b(p0 * rinv);
            pl[row * 72 + 16 + lr] = f2b(p1 * rinv);
            pl[row * 72 + 32 + lr] = f2b(p2 * rinv);
            pl[row * 72 + 48 + lr] = f2b(p3 * rinv);
        }
    }

    // ---- V pad rows (pos 49..63) -> 0, then tr-read V^T fragments ----
    asm volatile("s_waitcnt vmcnt(0)" ::: "memory");       // V GLDS landed
    if (lane < 60) {
        const int db = lane / 30, ix = lane % 30;
        f32x4 z = {0.f, 0.f, 0.f, 0.f};
        *reinterpret_cast<f32x4*>(vl + db * 1024 + 784 + ix * 8) = z;
    }
    asm volatile("s_waitcnt lgkmcnt(0)" ::: "memory");     // zeros + P stores done
    __builtin_amdgcn_sched_barrier(0);

    const unsigned VB = (unsigned)(unsigned long)
        (__attribute__((address_space(3))) u16*)vl;
    unsigned long long trv[2][2][2];                        // [kc][f2][half]
#pragma unroll
    for (int kc = 0; kc < 2; ++kc)
#pragma unroll
        for (int f2 = 0; f2 < 2; ++f2) {
            const unsigned va = VB + f2 * 2048 + kc * 1024 + lg * 256 + lr * 2;
            asm volatile("ds_read_b64_tr_b16 %0, %1"
                         : "=v"(trv[kc][f2][0]) : "v"(va));
            asm volatile("ds_read_b64_tr_b16 %0, %1 offset:128"
                         : "=v"(trv[kc][f2][1]) : "v"(va));
        }
    asm volatile("s_waitcnt lgkmcnt(0)" ::: "memory");
    __builtin_amdgcn_sched_barrier(0);

    // ---- PV ----
    f32x4 o[4][2] = {};
#pragma unroll
    for (int kc = 0; kc < 2; ++kc) {
#pragma unroll
        for (int fm = 0; fm < 4; ++fm) {
            const bf16x8 pa = *reinterpret_cast<const bf16x8*>(
                pl + (fm * 16 + lr) * 72 + kc * 32 + lg * 8);
#pragma unroll
            for (int f2 = 0; f2 < 2; ++f2) {
                union { unsigned long long q[2]; bf16x8 v; } u;
                u.q[0] = trv[kc][f2][0]; u.q[1] = trv[kc][f2][1];
                o[fm][f2] = MFMA(pa, u.v, o[fm][f2], 0, 0, 0);
            }
        }
    }

    // ---- window-reverse store ----
    const int b = win >> 10, rem = win & 1023, wy = rem >> 5, wx = rem & 31;
#pragma unroll
    for (int fm = 0; fm < 4; ++fm) {
#pragma unroll
        for (int r = 0; r < 4; ++r) {
            const int tok = fm * 16 + lg * 4 + r;
            if (tok > 48) continue;
            const int y = wy * 7 + tok / 7, xx = wx * 7 + tok % 7;
            const size_t mrow = ((size_t)(b * 224 + y)) * 224 + xx;
#pragma unroll
            for (int f2 = 0; f2 < 2; ++f2)
                outb[mrow * 256 + head * 32 + f2 * 16 + lr] = f2b(o[fm][f2][r]);
        }
    }
}

// ---------------------------------------------------------------------------
// Helpers
// ---------------------------------------------------------------------------
__global__ __launch_bounds__(256)
void cvt_w(const float* __restrict__ qw, const float* __restrict__ pw,
           const float* __restrict__ f1, const float* __restrict__ f2,
           u16* __restrict__ outw)
{
    const int t = blockIdx.x * 256 + threadIdx.x;  // 786432 total
    float v;
    if (t < 196608) v = qw[t];
    else if (t < 262144) v = pw[t - 196608];
    else if (t < 524288) v = f1[t - 262144];
    else v = f2[t - 524288];
    outw[t] = f2b(v);
}

// Bias in MFMA fragment layout: [head][fm][fn][lane][r]; col>48 -> -1e30.
__global__ __launch_bounds__(256)
void bias_pre(const float* __restrict__ btab, const int* __restrict__ relidx,
              float* __restrict__ biasF)
{
    const int t = blockIdx.x * 256 + threadIdx.x;   // 8192 total
    const int head = t >> 10, rem = t & 1023;
    const int fr = rem >> 6, lane = rem & 63;
    const int fm = fr >> 2, fn = fr & 3;
    const int lr = lane & 15, lg = lane >> 4;
    const int col = fn * 16 + lr;
    f32x4 o;
#pragma unroll
    for (int r = 0; r < 4; ++r) {
        int row = fm * 16 + lg * 4 + r; if (row > 48) row = 48;
        o[r] = (col > 48) ? -1e30f : btab[relidx[row * 49 + col] * 8 + head];
    }
    *reinterpret_cast<f32x4*>(biasF + t * 4) = o;
}

// ---------------------------------------------------------------------------
extern "C" void kernel_launch(void* const* d_in, const int* in_sizes, int n_in,
                              void* d_out, int out_size, void* d_ws, size_t ws_size,
                              hipStream_t stream)
{
    const float* x      = (const float*)d_in[0];
    const float* n1g    = (const float*)d_in[1];
    const float* n1b    = (const float*)d_in[2];
    const float* qkv_w  = (const float*)d_in[3];
    const float* qkv_b  = (const float*)d_in[4];
    const float* btab   = (const float*)d_in[5];
    const float* proj_w = (const float*)d_in[6];
    const float* proj_b = (const float*)d_in[7];
    const float* n2g    = (const float*)d_in[8];
    const float* n2b    = (const float*)d_in[9];
    const float* fc1_w  = (const float*)d_in[10];
    const float* fc1_b  = (const float*)d_in[11];
    const float* fc2_w  = (const float*)d_in[12];
    const float* fc2_b  = (const float*)d_in[13];
    const int*   relidx = (const int*)d_in[14];
    float* out = (float*)d_out;

    // workspace layout:
    //  [0, 1572864)            : bf16 weights
    //  [1572864, 1703936)      : bias fragments f32 (8 heads x 16 frags x 256)
    //  [1703936, +102760448)   : A region (bf16 token x 256): h / attn_out / h2
    //  [104464384, ...)        : R region: Q|K|V (308.3 MB), reused as MLP hidden
    char* ws = (char*)d_ws;
    u16*   wbf   = (u16*)ws;
    float* biasF = (float*)(ws + 1572864);
    u16*   hbuf  = (u16*)(ws + 1703936);
    u16*   rbuf  = (u16*)(ws + 1703936 + 102760448);
    const size_t r_avail = ws_size - (1703936 + 102760448);

    const u16* Wq  = wbf;
    const u16* Wp  = wbf + 196608;
    const u16* Wf1 = wbf + 262144;
    const u16* Wf2 = wbf + 524288;

    cvt_w<<<3072, 256, 0, stream>>>(qkv_w, proj_w, fc1_w, fc2_w, wbf);
    bias_pre<<<32, 256, 0, stream>>>(btab, relidx, biasF);
    layernorm_k<<<50176, 256, 0, stream>>>(x, n1g, n1b, hbuf);

    // QKV projection: M=200704 (784 m-tiles of 256), N=768 (6 n-tiles of 128)
    gemm_t<0, 4, 2><<<784 * 6, 512, 0, stream>>>(hbuf, Wq, qkv_b, 6, 256,
                                                 rbuf, nullptr, nullptr, nullptr, nullptr, nullptr);
    // window attention
    attn_win<<<8192, 256, 0, stream>>>(rbuf, biasF, hbuf);

    // proj + residual -> out (f32), fused LN2 -> hbuf (bf16); BM=128, BN=256
    gemm_t<1, 2, 4><<<1568, 512, 0, stream>>>(hbuf, Wp, proj_b, 1, 256,
                                              nullptr, out, x, n2g, n2b, hbuf);

    // MLP chunked at 100352 rows (hidden chunk ~205 MB, mostly L3-resident)
    long rows_per = 100352;
    if ((long)(r_avail / 2048) < rows_per) rows_per = 50176;
    for (long r0 = 0; r0 < TOKENS; r0 += rows_per) {
        const long rows = (TOKENS - r0 < rows_per) ? (TOKENS - r0) : rows_per;
        gemm_t<2, 4, 2><<<(int)((rows / 256) * 8), 512, 0, stream>>>(
            hbuf + r0 * 256, Wf1, fc1_b, 8, 256, rbuf, nullptr, nullptr, nullptr, nullptr, nullptr);
        gemm_t<3, 4, 2><<<(int)((rows / 256) * 2), 512, 0, stream>>>(
            rbuf, Wf2, fc2_b, 2, 1024, nullptr, out + r0 * 256, nullptr, nullptr, nullptr, nullptr);
    }
}

// Round 11
// 984.059 us; speedup vs baseline: 1.2112x; 1.0171x over previous
//
#include <hip/hip_runtime.h>

typedef unsigned short u16;
typedef __bf16 bf16x8 __attribute__((ext_vector_type(8)));
typedef float f32x4 __attribute__((ext_vector_type(4)));

#define TOKENS 200704
#define QK_ELEMS 51380224UL   // 32768 pairs * 49 * 32 (each of Q,K,V)

__device__ __forceinline__ u16 f2b(float f) {
    __bf16 h = (__bf16)f;                 // hw v_cvt (RTNE)
    return __builtin_bit_cast(u16, h);
}

#define GLDS(g, l) __builtin_amdgcn_global_load_lds( \
    (const __attribute__((address_space(1))) void*)(g), \
    (__attribute__((address_space(3))) void*)(l), 16, 0, 0)

#define MFMA __builtin_amdgcn_mfma_f32_16x16x32_bf16

// ---------------------------------------------------------------------------
// GEMM: C[m,n] = sum_k A[m,k]*W[n,k].  Tile BM x BN = (WR*64) x (WC*64),
// 8 waves (WR x WC grid of 64x64 wave-tiles, acc[4][4] = 64 regs), BK=32,
// double-buffered 48 KB LDS -> high occupancy. Counted-vmcnt pipeline;
// 4-slot XOR swizzle on the K-loop LDS (conflict-free, verified).
// bf16 epilogues (EPI 0/2) stage the output tile through the free A-LDS
// (128x128 u16 halves, chunk-XOR swizzled) and store with dwordx4 (16 B/lane)
// instead of 64 scalar 2 B stores per thread.
// EPI 0: qkv (+bias, q pre-scaled) -> (pair*49+pos)*32+d for Q,K,V
// EPI 1: proj: x2 = v+bias+res -> outf(f32) AND fused LN2 -> h2o(bf16)  [WC=4]
// EPI 2: fc1 (+bias, GELU -> bf16)   EPI 3: fc2 (+bias, outf +=)
// ---------------------------------------------------------------------------
template<int EPI, int WR, int WC>
__global__ __launch_bounds__(512, 4)
void gemm_t(const u16* __restrict__ A, const u16* __restrict__ W,
            const float* __restrict__ bias, int nt, int K,
            u16* __restrict__ outb, float* __restrict__ outf,
            const float* __restrict__ res,
            const float* __restrict__ g2, const float* __restrict__ b2,
            u16* __restrict__ h2o)
{
    constexpr int BM = WR * 64, BN = WC * 64;
    constexpr int ACH = BM / 16;            // A chunks (16 rows each)
    constexpr int TCH = (BM + BN) / 16;     // 24 total chunks
    __shared__ u16 As[2][BM * 32];
    __shared__ u16 Bs[2][BN * 32];
    __shared__ float red[EPI == 1 ? 2 * 128 * 4 : 1];

    const int tid  = threadIdx.x;
    const int wave = tid >> 6, lane = tid & 63;

    // bijective XCD-aware block swizzle (m204)
    const int nwg = gridDim.x, bidO = blockIdx.x;
    const int qq = nwg >> 3, rr = nwg & 7;
    const int xcd = bidO & 7, idxx = bidO >> 3;
    const int bid = (xcd < rr) ? (xcd * (qq + 1) + idxx)
                               : (rr * (qq + 1) + (xcd - rr) * qq + idxx);

    const int bm = bid / nt, bn = bid % nt;
    const long m0 = (long)bm * BM;
    const int  n0 = bn * BN;
    const int wr = wave / WC, wc = wave % WC;
    const int lr = lane & 15, lg = lane >> 4;
    const int ccol_s = (((lane & 3) ^ ((lane >> 3) & 3)) * 8);
    const int swzr = (lg ^ ((lr >> 1) & 3)) * 8;

    f32x4 acc[4][4] = {};

    auto stage = [&](int buf, int k0) {
#pragma unroll
        for (int p = 0; p < TCH / 8; ++p) {        // 3 GLDS per wave
            const int q = p * 8 + wave;
            const int rq = (q < ACH) ? q : q - ACH;
            const int row = rq * 16 + (lane >> 2);
            if (q < ACH)
                GLDS(A + (m0 + row) * (long)K + k0 + ccol_s, &As[buf][rq * 512]);
            else
                GLDS(W + (long)(n0 + row) * K + k0 + ccol_s, &Bs[buf][rq * 512]);
        }
    };

    auto compute = [&](int buf) {
        bf16x8 af[4], bfr[4];
#pragma unroll
        for (int fm = 0; fm < 4; ++fm)
            af[fm] = *reinterpret_cast<const bf16x8*>(
                &As[buf][(wr * 64 + fm * 16 + lr) * 32 + swzr]);
#pragma unroll
        for (int fn = 0; fn < 4; ++fn)
            bfr[fn] = *reinterpret_cast<const bf16x8*>(
                &Bs[buf][(wc * 64 + fn * 16 + lr) * 32 + swzr]);
        __builtin_amdgcn_s_setprio(1);
#pragma unroll
        for (int fm = 0; fm < 4; ++fm)
#pragma unroll
            for (int fn = 0; fn < 4; ++fn)
                acc[fm][fn] = MFMA(af[fm], bfr[fn], acc[fm][fn], 0, 0, 0);
        __builtin_amdgcn_s_setprio(0);
    };

    const int nk = K >> 5;                  // 8 (K=256) or 32 (K=1024)
    stage(0, 0);
    stage(1, 32);
    int k = 64;
    for (int t = 0; t < nk; ++t) {
        if (t == nk - 1) asm volatile("s_waitcnt vmcnt(0)" ::: "memory");
        else             asm volatile("s_waitcnt vmcnt(3)" ::: "memory");
        __builtin_amdgcn_s_barrier();
        __builtin_amdgcn_sched_barrier(0);
        compute(t & 1);
        __builtin_amdgcn_s_barrier();
        __builtin_amdgcn_sched_barrier(0);
        if (t + 2 < nk) {
            stage(t & 1, k); k += 32;
            __builtin_amdgcn_sched_barrier(0);
        }
    }

    if constexpr (EPI == 0 || EPI == 2) {
        // ---- staged coalesced bf16 store: two 128x128 u16 halves in As ----
        u16* st = &As[0][0];                       // 32 KB, exactly 128x128 u16
        float bb4[4], sc4[4];
#pragma unroll
        for (int fn = 0; fn < 4; ++fn) {
            const int n = n0 + wc * 64 + fn * 16 + lr;
            bb4[fn] = bias[n];
            sc4[fn] = (EPI == 0 && (n >> 8) == 0) ? 0.17677669529663687f : 1.0f;
        }
#pragma unroll
        for (int h = 0; h < 2; ++h) {
            if ((wr >> 1) == h) {                  // this wave owns rows of half h
#pragma unroll
                for (int fm = 0; fm < 4; ++fm) {
#pragma unroll
                    for (int r = 0; r < 4; ++r) {
                        const int lrow = (wr & 1) * 64 + fm * 16 + lg * 4 + r;
                        const int swb = ((lrow >> 2) & 3) << 1;
#pragma unroll
                        for (int fn = 0; fn < 4; ++fn) {
                            const int col = wc * 64 + fn * 16 + lr;
                            const int cs = (col >> 3) ^ swb;
                            float v = acc[fm][fn][r] + bb4[fn];
                            u16 w;
                            if (EPI == 0) {
                                w = f2b(v * sc4[fn]);
                            } else {
                                const float s = v * (1.5957691216f + 0.07135481627f * v * v);
                                w = f2b(v * __builtin_amdgcn_rcpf(1.0f + __expf(-s)));
                            }
                            st[lrow * 128 + cs * 8 + (col & 7)] = w;
                        }
                    }
                }
            }
            asm volatile("s_waitcnt lgkmcnt(0)" ::: "memory");
            __builtin_amdgcn_s_barrier();
#pragma unroll
            for (int it = 0; it < 4; ++it) {
                const int u = it * 512 + tid;      // 2048 row-chunks per half
                const int row = u >> 4, chunk = u & 15;
                const int cs = chunk ^ (((row >> 2) & 3) << 1);
                const bf16x8 val = *reinterpret_cast<const bf16x8*>(st + row * 128 + cs * 8);
                const long m = m0 + h * 128 + row;
                if (EPI == 0) {
                    const int gm = (int)m;
                    const int b = gm / 50176, rem = gm % 50176;
                    const int y = rem / 224, x = rem % 224;
                    const int win = (b * 32 + y / 7) * 32 + x / 7;
                    const int pos = (y % 7) * 7 + (x % 7);
                    const int n = n0 + (chunk << 3);
                    const int sec = n >> 8, hd = (n >> 5) & 7, dsub = n & 31;
                    *reinterpret_cast<bf16x8*>(outb + sec * QK_ELEMS + (size_t)win * 12544
                        + pos * 32 + hd * 1568 + dsub) = val;
                } else {
                    *reinterpret_cast<bf16x8*>(outb + m * 1024 + n0 + (chunk << 3)) = val;
                }
            }
            if (h == 0) {
                asm volatile("s_waitcnt lgkmcnt(0)" ::: "memory");
                __builtin_amdgcn_s_barrier();
            }
        }
    } else if constexpr (EPI == 1) {
        // proj + residual -> outf (f32); fused LN2 -> h2o (bf16). BM=128, WC=4.
        float g2c[4], b2c[4];
#pragma unroll
        for (int fn = 0; fn < 4; ++fn) {
            const int n = wc * 64 + fn * 16 + lr;          // n0 == 0 (nt==1)
            g2c[fn] = g2[n]; b2c[fn] = b2[n];
        }
#pragma unroll
        for (int fm = 0; fm < 4; ++fm) {
#pragma unroll
            for (int r = 0; r < 4; ++r) {
                const long m = m0 + wr * 64 + fm * 16 + lg * 4 + r;
                float s = 0.f, s2 = 0.f;
#pragma unroll
                for (int fn = 0; fn < 4; ++fn) {
                    const int n = wc * 64 + fn * 16 + lr;
                    const float x2 = acc[fm][fn][r] + bias[n] + res[m * 256 + n];
                    acc[fm][fn][r] = x2;
                    outf[m * 256 + n] = x2;
                    s += x2; s2 += x2 * x2;
                }
#pragma unroll
                for (int d = 1; d < 16; d <<= 1) { s += __shfl_xor(s, d); s2 += __shfl_xor(s2, d); }
                if (lr == 0) {
                    const int tok = wr * 64 + fm * 16 + lg * 4 + r;
                    red[(0 * 128 + tok) * 4 + wc] = s;
                    red[(1 * 128 + tok) * 4 + wc] = s2;
                }
            }
        }
        __syncthreads();
#pragma unroll
        for (int fm = 0; fm < 4; ++fm) {
#pragma unroll
            for (int r = 0; r < 4; ++r) {
                const int tok = wr * 64 + fm * 16 + lg * 4 + r;
                const float s = red[(0 * 128 + tok) * 4 + 0] + red[(0 * 128 + tok) * 4 + 1]
                              + red[(0 * 128 + tok) * 4 + 2] + red[(0 * 128 + tok) * 4 + 3];
                const float q = red[(1 * 128 + tok) * 4 + 0] + red[(1 * 128 + tok) * 4 + 1]
                              + red[(1 * 128 + tok) * 4 + 2] + red[(1 * 128 + tok) * 4 + 3];
                const float mu = s * 0.00390625f;
                const float rs = rsqrtf(q * 0.00390625f - mu * mu + 1e-5f);
                const long m = m0 + tok;
#pragma unroll
                for (int fn = 0; fn < 4; ++fn) {
                    const int n = wc * 64 + fn * 16 + lr;
                    h2o[m * 256 + n] = f2b((acc[fm][fn][r] - mu) * rs * g2c[fn] + b2c[fn]);
                }
            }
        }
    } else {
#pragma unroll
        for (int fm = 0; fm < 4; ++fm) {
#pragma unroll
            for (int r = 0; r < 4; ++r) {
                const long m = m0 + wr * 64 + fm * 16 + lg * 4 + r;
#pragma unroll
                for (int fn = 0; fn < 4; ++fn) {
                    const int n = n0 + wc * 64 + fn * 16 + lr;
                    outf[m * 256 + n] += acc[fm][fn][r] + bias[n];
                }
            }
        }
    }
}

// ---------------------------------------------------------------------------
// LayerNorm over C=256, f32 in -> bf16 out. 1 wave per token, 4 tokens/block.
// ---------------------------------------------------------------------------
__global__ __launch_bounds__(256)
void layernorm_k(const float* __restrict__ in, const float* __restrict__ g,
                 const float* __restrict__ bb, u16* __restrict__ out)
{
    const int token = blockIdx.x * 4 + (threadIdx.x >> 6);
    const int lane = threadIdx.x & 63;
    const float4 v = *reinterpret_cast<const float4*>(in + (size_t)token * 256 + lane * 4);
    float s  = v.x + v.y + v.z + v.w;
    float s2 = v.x * v.x + v.y * v.y + v.z * v.z + v.w * v.w;
#pragma unroll
    for (int m = 1; m < 64; m <<= 1) { s += __shfl_xor(s, m); s2 += __shfl_xor(s2, m); }
    const float mu  = s * (1.0f / 256.0f);
    const float var = s2 * (1.0f / 256.0f) - mu * mu;
    const float rs  = rsqrtf(var + 1e-5f);
    const float4 gv = *reinterpret_cast<const float4*>(g + lane * 4);
    const float4 bv = *reinterpret_cast<const float4*>(bb + lane * 4);
    ushort4 o;
    o.x = f2b((v.x - mu) * rs * gv.x + bv.x);
    o.y = f2b((v.y - mu) * rs * gv.y + bv.y);
    o.z = f2b((v.z - mu) * rs * gv.z + bv.z);
    o.w = f2b((v.w - mu) * rs * gv.w + bv.w);
    *reinterpret_cast<ushort4*>(out + (size_t)token * 256 + lane * 4) = o;
}

// ---------------------------------------------------------------------------
// Window attention: 1 wave per (window, head), fully wave-independent (no
// __syncthreads). Bias pre-baked in fragment layout (pads = -1e30). V staged
// via 4x global_load_lds into [2 dblk][64 pos][16 d] and consumed through
// ds_read_b64_tr_b16 (column-of-4x16-tile gather, offset:128 = +4 pos).
// ---------------------------------------------------------------------------
__global__ __launch_bounds__(256)
void attn_win(const u16* __restrict__ qkv, const float* __restrict__ biasF,
              u16* __restrict__ outb)
{
    __shared__ u16 plds[4][64 * 72];
    __shared__ u16 vlds[4][2048];
    const int wave = threadIdx.x >> 6, lane = threadIdx.x & 63;
    const int pair = blockIdx.x * 4 + wave;
    const int head = pair & 7, win = pair >> 3;
    const int lr = lane & 15, lg = lane >> 4;

    const u16* Q  = qkv + (size_t)pair * 1568;
    const u16* Kp = qkv + QK_ELEMS + (size_t)pair * 1568;
    const u16* Vp = qkv + 2 * QK_ELEMS + (size_t)pair * 1568;

    // ---- Q,K fragments (issued first = oldest vmcnt) ----
    bf16x8 qf[4], kf[4];
#pragma unroll
    for (int f = 0; f < 4; ++f) {
        int n = f * 16 + lr; n = n > 48 ? 48 : n;
        qf[f] = *reinterpret_cast<const bf16x8*>(Q  + n * 32 + lg * 8);
        kf[f] = *reinterpret_cast<const bf16x8*>(Kp + n * 32 + lg * 8);
    }

    // ---- V staging: 4x global_load_lds -> [db][pos][16] (pads zeroed later) ----
    u16* vl = &vlds[wave][0];
    {
        const int posh = lane >> 1, dsub = (lane & 1) * 8;
#pragma unroll
        for (int db = 0; db < 2; ++db)
#pragma unroll
            for (int half = 0; half < 2; ++half) {
                int pos = half * 32 + posh; if (pos > 48) pos = 48;   // clamp source
                GLDS(Vp + pos * 32 + db * 16 + dsub, vl + db * 1024 + half * 512);
            }
    }

    // ---- QK^T ----
    f32x4 s[4][4] = {};
#pragma unroll
    for (int fm = 0; fm < 4; ++fm)
#pragma unroll
        for (int fn = 0; fn < 4; ++fn)
            s[fm][fn] = MFMA(qf[fm], kf[fn], s[fm][fn], 0, 0, 0);

    // ---- softmax: bias fragments coalesced, pads pre-masked ----
    const float* bfh = biasF + head * 4096;        // 16 frags * 256 floats
    u16* pl = &plds[wave][0];
#pragma unroll
    for (int fm = 0; fm < 4; ++fm) {
        f32x4 bb[4];
#pragma unroll
        for (int fn = 0; fn < 4; ++fn)
            bb[fn] = *reinterpret_cast<const f32x4*>(bfh + ((fm * 4 + fn) << 8) + (lane << 2));
#pragma unroll
        for (int r = 0; r < 4; ++r) {
            const int row = fm * 16 + lg * 4 + r;
            float v0 = s[fm][0][r] + bb[0][r];
            float v1 = s[fm][1][r] + bb[1][r];
            float v2 = s[fm][2][r] + bb[2][r];
            float v3 = s[fm][3][r] + bb[3][r];
            float mx = fmaxf(fmaxf(v0, v1), fmaxf(v2, v3));
#pragma unroll
            for (int d = 1; d < 16; d <<= 1) mx = fmaxf(mx, __shfl_xor(mx, d));
            const float p0 = __expf(v0 - mx), p1 = __expf(v1 - mx);
            const float p2 = __expf(v2 - mx), p3 = __expf(v3 - mx);
            float sum = p0 + p1 + p2 + p3;
#pragma unroll
            for (int d = 1; d < 16; d <<= 1) sum += __shfl_xor(sum, d);
            const float rinv = __builtin_amdgcn_rcpf(sum);
            pl[row * 72 +  0 + lr] = f2b(p0 * rinv);
            pl[row * 72 + 16 + lr] = f2b(p1 * rinv);
            pl[row * 72 + 32 + lr] = f2b(p2 * rinv);
            pl[row * 72 + 48 + lr] = f2b(p3 * rinv);
        }
    }

    // ---- V pad rows (pos 49..63) -> 0, then tr-read V^T fragments ----
    asm volatile("s_waitcnt vmcnt(0)" ::: "memory");       // V GLDS landed
    if (lane < 60) {
        const int db = lane / 30, ix = lane % 30;
        f32x4 z = {0.f, 0.f, 0.f, 0.f};
        *reinterpret_cast<f32x4*>(vl + db * 1024 + 784 + ix * 8) = z;
    }
    asm volatile("s_waitcnt lgkmcnt(0)" ::: "memory");     // zeros + P stores done
    __builtin_amdgcn_sched_barrier(0);

    const unsigned VB = (unsigned)(unsigned long)
        (__attribute__((address_space(3))) u16*)vl;
    unsigned long long trv[2][2][2];                        // [kc][f2][half]
#pragma unroll
    for (int kc = 0; kc < 2; ++kc)
#pragma unroll
        for (int f2 = 0; f2 < 2; ++f2) {
            const unsigned va = VB + f2 * 2048 + kc * 1024 + lg * 256 + lr * 2;
            asm volatile("ds_read_b64_tr_b16 %0, %1"
                         : "=v"(trv[kc][f2][0]) : "v"(va));
            asm volatile("ds_read_b64_tr_b16 %0, %1 offset:128"
                         : "=v"(trv[kc][f2][1]) : "v"(va));
        }
    asm volatile("s_waitcnt lgkmcnt(0)" ::: "memory");
    __builtin_amdgcn_sched_barrier(0);

    // ---- PV ----
    f32x4 o[4][2] = {};
#pragma unroll
    for (int kc = 0; kc < 2; ++kc) {
#pragma unroll
        for (int fm = 0; fm < 4; ++fm) {
            const bf16x8 pa = *reinterpret_cast<const bf16x8*>(
                pl + (fm * 16 + lr) * 72 + kc * 32 + lg * 8);
#pragma unroll
            for (int f2 = 0; f2 < 2; ++f2) {
                union { unsigned long long q[2]; bf16x8 v; } u;
                u.q[0] = trv[kc][f2][0]; u.q[1] = trv[kc][f2][1];
                o[fm][f2] = MFMA(pa, u.v, o[fm][f2], 0, 0, 0);
            }
        }
    }

    // ---- window-reverse store ----
    const int b = win >> 10, rem = win & 1023, wy = rem >> 5, wx = rem & 31;
#pragma unroll
    for (int fm = 0; fm < 4; ++fm) {
#pragma unroll
        for (int r = 0; r < 4; ++r) {
            const int tok = fm * 16 + lg * 4 + r;
            if (tok > 48) continue;
            const int y = wy * 7 + tok / 7, xx = wx * 7 + tok % 7;
            const size_t mrow = ((size_t)(b * 224 + y)) * 224 + xx;
#pragma unroll
            for (int f2 = 0; f2 < 2; ++f2)
                outb[mrow * 256 + head * 32 + f2 * 16 + lr] = f2b(o[fm][f2][r]);
        }
    }
}

// ---------------------------------------------------------------------------
// Helpers
// ---------------------------------------------------------------------------
__global__ __launch_bounds__(256)
void cvt_w(const float* __restrict__ qw, const float* __restrict__ pw,
           const float* __restrict__ f1, const float* __restrict__ f2,
           u16* __restrict__ outw)
{
    const int t = blockIdx.x * 256 + threadIdx.x;  // 786432 total
    float v;
    if (t < 196608) v = qw[t];
    else if (t < 262144) v = pw[t - 196608];
    else if (t < 524288) v = f1[t - 262144];
    else v = f2[t - 524288];
    outw[t] = f2b(v);
}

// Bias in MFMA fragment layout: [head][fm][fn][lane][r]; col>48 -> -1e30.
__global__ __launch_bounds__(256)
void bias_pre(const float* __restrict__ btab, const int* __restrict__ relidx,
              float* __restrict__ biasF)
{
    const int t = blockIdx.x * 256 + threadIdx.x;   // 8192 total
    const int head = t >> 10, rem = t & 1023;
    const int fr = rem >> 6, lane = rem & 63;
    const int fm = fr >> 2, fn = fr & 3;
    const int lr = lane & 15, lg = lane >> 4;
    const int col = fn * 16 + lr;
    f32x4 o;
#pragma unroll
    for (int r = 0; r < 4; ++r) {
        int row = fm * 16 + lg * 4 + r; if (row > 48) row = 48;
        o[r] = (col > 48) ? -1e30f : btab[relidx[row * 49 + col] * 8 + head];
    }
    *reinterpret_cast<f32x4*>(biasF + t * 4) = o;
}

// ---------------------------------------------------------------------------
extern "C" void kernel_launch(void* const* d_in, const int* in_sizes, int n_in,
                              void* d_out, int out_size, void* d_ws, size_t ws_size,
                              hipStream_t stream)
{
    const float* x      = (const float*)d_in[0];
    const float* n1g    = (const float*)d_in[1];
    const float* n1b    = (const float*)d_in[2];
    const float* qkv_w  = (const float*)d_in[3];
    const float* qkv_b  = (const float*)d_in[4];
    const float* btab   = (const float*)d_in[5];
    const float* proj_w = (const float*)d_in[6];
    const float* proj_b = (const float*)d_in[7];
    const float* n2g    = (const float*)d_in[8];
    const float* n2b    = (const float*)d_in[9];
    const float* fc1_w  = (const float*)d_in[10];
    const float* fc1_b  = (const float*)d_in[11];
    const float* fc2_w  = (const float*)d_in[12];
    const float* fc2_b  = (const float*)d_in[13];
    const int*   relidx = (const int*)d_in[14];
    float* out = (float*)d_out;

    // workspace layout:
    //  [0, 1572864)            : bf16 weights
    //  [1572864, 1703936)      : bias fragments f32 (8 heads x 16 frags x 256)
    //  [1703936, +102760448)   : A region (bf16 token x 256): h / attn_out / h2
    //  [104464384, ...)        : R region: Q|K|V (308.3 MB), reused as MLP hidden
    char* ws = (char*)d_ws;
    u16*   wbf   = (u16*)ws;
    float* biasF = (float*)(ws + 1572864);
    u16*   hbuf  = (u16*)(ws + 1703936);
    u16*   rbuf  = (u16*)(ws + 1703936 + 102760448);
    const size_t r_avail = ws_size - (1703936 + 102760448);

    const u16* Wq  = wbf;
    const u16* Wp  = wbf + 196608;
    const u16* Wf1 = wbf + 262144;
    const u16* Wf2 = wbf + 524288;

    cvt_w<<<3072, 256, 0, stream>>>(qkv_w, proj_w, fc1_w, fc2_w, wbf);
    bias_pre<<<32, 256, 0, stream>>>(btab, relidx, biasF);
    layernorm_k<<<50176, 256, 0, stream>>>(x, n1g, n1b, hbuf);

    // QKV projection: M=200704 (784 m-tiles of 256), N=768 (6 n-tiles of 128)
    gemm_t<0, 4, 2><<<784 * 6, 512, 0, stream>>>(hbuf, Wq, qkv_b, 6, 256,
                                                 rbuf, nullptr, nullptr, nullptr, nullptr, nullptr);
    // window attention
    attn_win<<<8192, 256, 0, stream>>>(rbuf, biasF, hbuf);

    // proj + residual -> out (f32), fused LN2 -> hbuf (bf16); BM=128, BN=256
    gemm_t<1, 2, 4><<<1568, 512, 0, stream>>>(hbuf, Wp, proj_b, 1, 256,
                                              nullptr, out, x, n2g, n2b, hbuf);

    // MLP chunked at 100352 rows (hidden chunk ~205 MB, mostly L3-resident)
    long rows_per = 100352;
    if ((long)(r_avail / 2048) < rows_per) rows_per = 50176;
    for (long r0 = 0; r0 < TOKENS; r0 += rows_per) {
        const long rows = (TOKENS - r0 < rows_per) ? (TOKENS - r0) : rows_per;
        gemm_t<2, 4, 2><<<(int)((rows / 256) * 8), 512, 0, stream>>>(
            hbuf + r0 * 256, Wf1, fc1_b, 8, 256, rbuf, nullptr, nullptr, nullptr, nullptr, nullptr);
        gemm_t<3, 4, 2><<<(int)((rows / 256) * 2), 512, 0, stream>>>(
            rbuf, Wf2, fc2_b, 2, 1024, nullptr, out + r0 * 256, nullptr, nullptr, nullptr, nullptr);
    }
}